// Round 1
// baseline (1647.851 us; speedup 1.0000x reference)
//
#include <hip/hip_runtime.h>

// ScaledDotProductAttention: B=4,H=8,L=2048,DK=DV=32
// out = [context (B,H,L,DV) | scores (B,H,L,L)] f32, concatenated.
// Flash-style single pass: one block = 64 query rows of one (b,h); 4 waves,
// each wave owns 16 rows. K-loop over 64-key tiles. Split-bf16 (hi+lo)
// 3-term MFMA products for f32-quality accuracy on 16x16x32_bf16 MFMA.
// NOTE: attn_mask (bool in reference) is read as int32 per harness doc
// ("integer -> const int*"). If output-1 absmax ~1e9, switch to uint8.

#define NB 4
#define NH 8
#define SL 2048
#define DKx 32
#define DVx 32
#define BM 64
#define BN 64
#define SCALE 0.17677669529663687f

typedef __bf16 bf16x8 __attribute__((ext_vector_type(8)));
typedef float f32x4 __attribute__((ext_vector_type(4)));
typedef short s16x4 __attribute__((ext_vector_type(4)));

union BF8 { short s[8]; bf16x8 v; };

__device__ __forceinline__ short f2bf(float x) {
  union { float f; unsigned u; } c; c.f = x;
  unsigned r = c.u + 0x7FFFu + ((c.u >> 16) & 1u);
  return (short)(r >> 16);
}
__device__ __forceinline__ float bf2f(short h) {
  union { float f; unsigned u; } c; c.u = ((unsigned)(unsigned short)h) << 16;
  return c.f;
}

__global__ __launch_bounds__(256, 4)
void fa_kernel(const float* __restrict__ Q, const float* __restrict__ K,
               const float* __restrict__ V, const int* __restrict__ mask,
               const float* __restrict__ res, float* __restrict__ ctx,
               float* __restrict__ scores)
{
  // Padded LDS: +8 shorts per row -> 16B-aligned b128 reads, <=2-way bank conflicts (free).
  __shared__ short Khi[BN][40], Klo[BN][40];      // [key][k]
  __shared__ short Vhi[DVx][72], Vlo[DVx][72];    // [v][key] (transposed for B-frag)
  __shared__ short Phi[4][16][72], Plo[4][16][72];// per-wave [m][key]

  const int tid  = threadIdx.x;
  const int w    = tid >> 6;
  const int lane = tid & 63;
  const int q    = lane >> 4;    // quad
  const int t16  = lane & 15;
  const int bh = blockIdx.y, qt = blockIdx.x;

  // Persistent Q A-fragment (split hi/lo): A[m=t16][k=q*8+j]
  const float* qp = Q + ((size_t)bh * SL + qt * BM + w * 16 + t16) * DKx + q * 8;
  BF8 qhi, qlo;
#pragma unroll
  for (int j = 0; j < 8; ++j) {
    float x = qp[j];
    short h = f2bf(x);
    qhi.s[j] = h;
    qlo.s[j] = f2bf(x - bf2f(h));
  }

  f32x4 accO[2];
  accO[0] = (f32x4)(0.f); accO[1] = (f32x4)(0.f);
  float m_i[4] = { -INFINITY, -INFINITY, -INFINITY, -INFINITY };
  float l_i[4] = { 0.f, 0.f, 0.f, 0.f };

  // This lane's 4 query rows (flattened over b,h): rows qrow0 .. qrow0+3
  const int qrow0 = bh * SL + qt * BM + w * 16 + q * 4;

  for (int kt = 0; kt < SL / BN; ++kt) {
    __syncthreads();  // protect K/V LDS from previous iteration's readers

    // ---- stage K (split bf16) and V (transposed, split bf16) ----
#pragma unroll
    for (int it = 0; it < 2; ++it) {
      int e  = tid + it * 256;        // 0..511
      int n  = e >> 3;                // key row 0..63
      int c4 = (e & 7) * 4;           // element quad 0..28
      const float4 kv = *(const float4*)(K + ((size_t)bh * SL + kt * BN + n) * DKx + c4);
      float ka[4] = { kv.x, kv.y, kv.z, kv.w };
      s16x4 hh, ll;
#pragma unroll
      for (int j = 0; j < 4; ++j) {
        short h = f2bf(ka[j]);
        hh[j] = h;
        ll[j] = f2bf(ka[j] - bf2f(h));
      }
      *(s16x4*)&Khi[n][c4] = hh;
      *(s16x4*)&Klo[n][c4] = ll;

      const float4 vv = *(const float4*)(V + ((size_t)bh * SL + kt * BN + n) * DVx + c4);
      float va[4] = { vv.x, vv.y, vv.z, vv.w };
#pragma unroll
      for (int j = 0; j < 4; ++j) {
        short h = f2bf(va[j]);
        Vhi[c4 + j][n] = h;
        Vlo[c4 + j][n] = f2bf(va[j] - bf2f(h));
      }
    }
    __syncthreads();

    // ---- S = Q K^T (split-bf16, 3 MFMA terms per 16x16 tile) ----
    f32x4 accs[4];
#pragma unroll
    for (int c = 0; c < 4; ++c) accs[c] = (f32x4)(0.f);
#pragma unroll
    for (int c = 0; c < 4; ++c) {
      bf16x8 kh = *(const bf16x8*)&Khi[c * 16 + t16][q * 8];
      bf16x8 kl = *(const bf16x8*)&Klo[c * 16 + t16][q * 8];
      accs[c] = __builtin_amdgcn_mfma_f32_16x16x32_bf16(qhi.v, kh, accs[c], 0, 0, 0);
      accs[c] = __builtin_amdgcn_mfma_f32_16x16x32_bf16(qlo.v, kh, accs[c], 0, 0, 0);
      accs[c] = __builtin_amdgcn_mfma_f32_16x16x32_bf16(qhi.v, kl, accs[c], 0, 0, 0);
    }

    // ---- scale + res + mask, stream scores out ----
    float sv[4][4];  // [c][i]
    const int col0 = kt * BN + t16;
#pragma unroll
    for (int c = 0; c < 4; ++c) {
#pragma unroll
      for (int i = 0; i < 4; ++i) {
        size_t idx = (size_t)(qrow0 + i) * SL + col0 + c * 16;
        float s = accs[c][i] * SCALE + res[idx];
        s = mask[idx] ? -1.0e9f : s;
        scores[idx] = s;
        sv[c][i] = s;
      }
    }

    // ---- online softmax (row reductions across 16 lanes of each quad) ----
    float pvv[4][4];
    float alpha[4];
#pragma unroll
    for (int i = 0; i < 4; ++i) {
      float rm = fmaxf(fmaxf(sv[0][i], sv[1][i]), fmaxf(sv[2][i], sv[3][i]));
      rm = fmaxf(rm, __shfl_xor(rm, 1));
      rm = fmaxf(rm, __shfl_xor(rm, 2));
      rm = fmaxf(rm, __shfl_xor(rm, 4));
      rm = fmaxf(rm, __shfl_xor(rm, 8));
      float mn = fmaxf(m_i[i], rm);
      float a  = __expf(m_i[i] - mn);
      m_i[i] = mn;
      alpha[i] = a;
      float rs = 0.f;
#pragma unroll
      for (int c = 0; c < 4; ++c) {
        float p = __expf(sv[c][i] - mn);
        pvv[c][i] = p;
        rs += p;
      }
      rs += __shfl_xor(rs, 1);
      rs += __shfl_xor(rs, 2);
      rs += __shfl_xor(rs, 4);
      rs += __shfl_xor(rs, 8);
      l_i[i] = l_i[i] * a + rs;
    }
#pragma unroll
    for (int nc = 0; nc < 2; ++nc)
#pragma unroll
      for (int i = 0; i < 4; ++i) accO[nc][i] *= alpha[i];

    // ---- P: C-layout -> LDS -> A-layout (split bf16) ----
#pragma unroll
    for (int c = 0; c < 4; ++c) {
#pragma unroll
      for (int i = 0; i < 4; ++i) {
        short h = f2bf(pvv[c][i]);
        Phi[w][q * 4 + i][c * 16 + t16] = h;
        Plo[w][q * 4 + i][c * 16 + t16] = f2bf(pvv[c][i] - bf2f(h));
      }
    }
    // (same-wave LDS write->read: lgkmcnt ordering, no barrier needed)

    // ---- O += P V (split-bf16, 3 terms) ----
#pragma unroll
    for (int kc = 0; kc < 2; ++kc) {
      bf16x8 ph = *(const bf16x8*)&Phi[w][t16][kc * 32 + q * 8];
      bf16x8 pl = *(const bf16x8*)&Plo[w][t16][kc * 32 + q * 8];
#pragma unroll
      for (int nc = 0; nc < 2; ++nc) {
        bf16x8 vh = *(const bf16x8*)&Vhi[nc * 16 + t16][kc * 32 + q * 8];
        bf16x8 vl = *(const bf16x8*)&Vlo[nc * 16 + t16][kc * 32 + q * 8];
        accO[nc] = __builtin_amdgcn_mfma_f32_16x16x32_bf16(ph, vh, accO[nc], 0, 0, 0);
        accO[nc] = __builtin_amdgcn_mfma_f32_16x16x32_bf16(pl, vh, accO[nc], 0, 0, 0);
        accO[nc] = __builtin_amdgcn_mfma_f32_16x16x32_bf16(ph, vl, accO[nc], 0, 0, 0);
      }
    }
  }

  // ---- epilogue: context = O / l ----
#pragma unroll
  for (int nc = 0; nc < 2; ++nc) {
#pragma unroll
    for (int i = 0; i < 4; ++i) {
      float o = accO[nc][i] / l_i[i];
      ctx[(size_t)(qrow0 + i) * DVx + nc * 16 + t16] = o;
    }
  }
}

extern "C" void kernel_launch(void* const* d_in, const int* in_sizes, int n_in,
                              void* d_out, int out_size, void* d_ws, size_t ws_size,
                              hipStream_t stream) {
  const float* Q    = (const float*)d_in[0];
  const float* K    = (const float*)d_in[1];
  const float* V    = (const float*)d_in[2];
  const int*   mask = (const int*)d_in[3];   // bool mask, assumed int32 on device
  const float* res  = (const float*)d_in[4];
  float* ctx    = (float*)d_out;
  float* scores = (float*)d_out + (size_t)NB * NH * SL * DVx;

  dim3 grid(SL / BM, NB * NH);
  fa_kernel<<<grid, dim3(256), 0, stream>>>(Q, K, V, mask, res, ctx, scores);
}